// Round 4
// baseline (112.724 us; speedup 1.0000x reference)
//
#include <hip/hip_runtime.h>

// SparsTriangularUpdate — round 4: kill the serial shuffle chain.
//
// Closed form (verified): c[t] = a[:,t*16,:]*b[:,t*16,:];
//   k[:,t*16+s,:] = sum_{m=s+2}^{16} c[:,(t+m)%4096,:]  (s=0..15; s=15 -> 0)
//
// kern_out is barrier-free: each wave owns 16 rows end-to-end.
//   x loaded directly in A-fragment layout -> LN via 2 shuffles -> afx (no LDS)
//   gate = sigmoid(xn@Wgo^T) via MFMA (cbuf loads in flight underneath)
//   scan: 15 serial f32 adds -> bf16 k rows in wave-private LDS
//   k-LN: fragment-layout ds_read + 2 shuffles -> afk in-reg
//   h = kn@Wlo^T via MFMA; out = gate*h

#define BB 2
#define NN 65536
#define DD 128
#define CC 128
#define NA 4096
#define STR 16
#define WSZ 16384   // elements per weight matrix

typedef short short2v __attribute__((ext_vector_type(2)));
typedef short short8v __attribute__((ext_vector_type(8)));
typedef __bf16 bf16x8 __attribute__((ext_vector_type(8)));
typedef float f32x4 __attribute__((ext_vector_type(4)));
typedef float f32x2 __attribute__((ext_vector_type(2)));

__device__ __forceinline__ float sigf(float v) { return 1.0f / (1.0f + __expf(-v)); }
__device__ __forceinline__ short f2bf(float f) {
    union { float f; unsigned u; } v; v.f = f;
    unsigned r = (v.u + 0x7FFFu + ((v.u >> 16) & 1u)) >> 16;   // RTNE
    return (short)r;
}
__device__ __forceinline__ float bf2f(short b) {
    union { unsigned u; float f; } v; v.u = ((unsigned)(unsigned short)b) << 16;
    return v.f;
}
__device__ __forceinline__ bf16x8 s2b(short8v s) {
    union { short8v s; bf16x8 b; } u; u.s = s; return u.b;
}

__global__ __launch_bounds__(256)
void kern_wcvt(const float* __restrict__ Wla, const float* __restrict__ Wga,
               const float* __restrict__ Wlb, const float* __restrict__ Wgb,
               const float* __restrict__ Wgo, const float* __restrict__ Wlo,
               short* __restrict__ wbf)
{
    const int i = blockIdx.x * 256 + threadIdx.x;
    wbf[i]           = f2bf(Wla[i]);
    wbf[WSZ + i]     = f2bf(Wga[i]);
    wbf[2 * WSZ + i] = f2bf(Wlb[i]);
    wbf[3 * WSZ + i] = f2bf(Wgb[i]);
    wbf[4 * WSZ + i] = f2bf(Wgo[i]);
    wbf[5 * WSZ + i] = f2bf(Wlo[i]);
}

__global__ __launch_bounds__(64)
void kern_ab(const float* __restrict__ x,
             const float* __restrict__ lnw, const float* __restrict__ lnb,
             const short* __restrict__ wbf,
             const float* __restrict__ bla, const float* __restrict__ bga,
             const float* __restrict__ blb, const float* __restrict__ bgb,
             float* __restrict__ cbuf)
{
    const int l     = threadIdx.x;            // 0..63
    const int bid   = blockIdx.x;             // BB*512
    const int batch = bid >> 9;
    const int t0    = ((bid & 511) >> 1) << 4;
    const int nt0   = (bid & 1) * 4;           // nt half: cols [nt0*16, +64)
    const int lr    = l & 15;
    const int q     = l >> 4;

    const float* xr = x + ((size_t)batch * NN + (size_t)(t0 + lr) * STR) * DD + q * 8;
    f32x4 v[4][2];
    #pragma unroll
    for (int kk = 0; kk < 4; ++kk) {
        v[kk][0] = *(const f32x4*)(xr + kk * 32);
        v[kk][1] = *(const f32x4*)(xr + kk * 32 + 4);
    }
    float s = 0.f, ss = 0.f;
    #pragma unroll
    for (int kk = 0; kk < 4; ++kk)
        #pragma unroll
        for (int h = 0; h < 2; ++h)
            #pragma unroll
            for (int j = 0; j < 4; ++j) { const float f = v[kk][h][j]; s += f; ss += f * f; }
    s += __shfl_xor(s, 16); ss += __shfl_xor(ss, 16);
    s += __shfl_xor(s, 32); ss += __shfl_xor(ss, 32);
    const float mu = s * (1.0f / 128.0f);
    const float rs = rsqrtf(ss * (1.0f / 128.0f) - mu * mu + 1e-5f);

    bf16x8 af[4];
    #pragma unroll
    for (int kk = 0; kk < 4; ++kk) {
        const f32x4 w0 = *(const f32x4*)(lnw + kk * 32 + q * 8);
        const f32x4 w1 = *(const f32x4*)(lnw + kk * 32 + q * 8 + 4);
        const f32x4 b0 = *(const f32x4*)(lnb + kk * 32 + q * 8);
        const f32x4 b1 = *(const f32x4*)(lnb + kk * 32 + q * 8 + 4);
        short8v t;
        #pragma unroll
        for (int j = 0; j < 4; ++j) {
            t[j]     = f2bf((v[kk][0][j] - mu) * rs * w0[j] + b0[j]);
            t[4 + j] = f2bf((v[kk][1][j] - mu) * rs * w1[j] + b1[j]);
        }
        af[kk] = s2b(t);
    }

    const short* wla = wbf;
    const short* wga = wbf + WSZ;
    const short* wlb = wbf + 2 * WSZ;
    const short* wgb = wbf + 3 * WSZ;

    #pragma unroll
    for (int nt = 0; nt < 4; ++nt) {
        const int col = (nt0 + nt) * 16 + lr;
        const size_t woff = (size_t)col * DD + q * 8;
        f32x4 ala = {0.f,0.f,0.f,0.f}, aga = {0.f,0.f,0.f,0.f};
        f32x4 alb = {0.f,0.f,0.f,0.f}, agb = {0.f,0.f,0.f,0.f};
        #pragma unroll
        for (int kk = 0; kk < 4; ++kk) {
            ala = __builtin_amdgcn_mfma_f32_16x16x32_bf16(af[kk], *(const bf16x8*)(wla + woff + kk * 32), ala, 0, 0, 0);
            aga = __builtin_amdgcn_mfma_f32_16x16x32_bf16(af[kk], *(const bf16x8*)(wga + woff + kk * 32), aga, 0, 0, 0);
            alb = __builtin_amdgcn_mfma_f32_16x16x32_bf16(af[kk], *(const bf16x8*)(wlb + woff + kk * 32), alb, 0, 0, 0);
            agb = __builtin_amdgcn_mfma_f32_16x16x32_bf16(af[kk], *(const bf16x8*)(wgb + woff + kk * 32), agb, 0, 0, 0);
        }
        const float xla = bla[col], xga = bga[col], xlb = blb[col], xgb = bgb[col];
        #pragma unroll
        for (int r = 0; r < 4; ++r) {
            const float av = sigf(aga[r] + xga) * (ala[r] + xla);
            const float bv = sigf(agb[r] + xgb) * (alb[r] + xlb);
            cbuf[((size_t)batch * NA + t0 + q * 4 + r) * CC + col] = av * bv;
        }
    }
}

__global__ __launch_bounds__(256, 4)
void kern_out(const float* __restrict__ x,
              const float* __restrict__ lnw,  const float* __restrict__ lnb,
              const float* __restrict__ lnow, const float* __restrict__ lnob,
              const short* __restrict__ wbf,  const float* __restrict__ bgo,
              const float* __restrict__ blo,
              const float* __restrict__ cbuf, float* __restrict__ out)
{
    __shared__ short kls[4][16][136];          // wave-private k tiles
    const int tid   = threadIdx.x;
    const int batch = blockIdx.x >> 10;
    const int ibb   = blockIdx.x & 1023;
    const int row0  = ibb * 64;
    const int t0    = ibb * 4;

    const int wv = tid >> 6, l = tid & 63;
    const int lr = l & 15, lk = l >> 4;
    const int t  = t0 + wv;

    // ---- issue x loads in A-fragment layout ----
    const float* xr = x + ((size_t)batch * NN + row0 + wv * 16 + lr) * DD + lk * 8;
    f32x4 v[4][2];
    #pragma unroll
    for (int kk = 0; kk < 4; ++kk) {
        v[kk][0] = *(const f32x4*)(xr + kk * 32);
        v[kk][1] = *(const f32x4*)(xr + kk * 32 + 4);
    }

    // ---- issue all 15 cbuf loads (in flight under LN + gate MFMAs) ----
    const int c2 = l * 2;
    f32x2 cv[15];
    #pragma unroll
    for (int s = 0; s < 15; ++s)
        cv[s] = *(const f32x2*)(cbuf + ((size_t)batch * NA + ((t + s + 2) & (NA - 1))) * CC + c2);

    // ---- LN(x): 2 shuffles, normalize in-reg -> afx ----
    float s = 0.f, ss = 0.f;
    #pragma unroll
    for (int kk = 0; kk < 4; ++kk)
        #pragma unroll
        for (int h = 0; h < 2; ++h)
            #pragma unroll
            for (int j = 0; j < 4; ++j) { const float f = v[kk][h][j]; s += f; ss += f * f; }
    s += __shfl_xor(s, 16); ss += __shfl_xor(ss, 16);
    s += __shfl_xor(s, 32); ss += __shfl_xor(ss, 32);
    const float mu = s * (1.0f / 128.0f);
    const float rs = rsqrtf(ss * (1.0f / 128.0f) - mu * mu + 1e-5f);

    bf16x8 afx[4];
    #pragma unroll
    for (int kk = 0; kk < 4; ++kk) {
        const f32x4 w0 = *(const f32x4*)(lnw + kk * 32 + lk * 8);
        const f32x4 w1 = *(const f32x4*)(lnw + kk * 32 + lk * 8 + 4);
        const f32x4 b0 = *(const f32x4*)(lnb + kk * 32 + lk * 8);
        const f32x4 b1 = *(const f32x4*)(lnb + kk * 32 + lk * 8 + 4);
        short8v o;
        #pragma unroll
        for (int j = 0; j < 4; ++j) {
            o[j]     = f2bf((v[kk][0][j] - mu) * rs * w0[j] + b0[j]);
            o[4 + j] = f2bf((v[kk][1][j] - mu) * rs * w1[j] + b1[j]);
        }
        afx[kk] = s2b(o);
    }

    // ---- gate = sigmoid(xn @ Wgo^T + bgo) via MFMA ----
    const short* wgo_bf = wbf + 4 * WSZ;
    const short* wlo_bf = wbf + 5 * WSZ;
    float gate[8][4];
    #pragma unroll
    for (int nt = 0; nt < 8; ++nt) {
        const size_t woff = (size_t)(nt * 16 + lr) * DD + lk * 8;
        f32x4 a0 = {0.f, 0.f, 0.f, 0.f};
        #pragma unroll
        for (int kk = 0; kk < 4; ++kk)
            a0 = __builtin_amdgcn_mfma_f32_16x16x32_bf16(afx[kk], *(const bf16x8*)(wgo_bf + woff + kk * 32), a0, 0, 0, 0);
        const float bg = bgo[nt * 16 + lr];
        #pragma unroll
        for (int r = 0; r < 4; ++r) gate[nt][r] = sigf(a0[r] + bg);
    }

    // ---- scan: 15 serial adds -> bf16 k in wave-private LDS ----
    {
        short2v z = {0, 0};
        *(short2v*)&kls[wv][15][c2] = z;
        float s0 = 0.f, s1 = 0.f;
        #pragma unroll
        for (int sx = 14; sx >= 0; --sx) {
            s0 += cv[sx][0]; s1 += cv[sx][1];
            short2v o; o[0] = f2bf(s0); o[1] = f2bf(s1);
            *(short2v*)&kls[wv][sx][c2] = o;
        }
    }

    // ---- k-LN: fragment-layout read, 2 shuffles, normalize -> afk ----
    short8v kraw[4];
    #pragma unroll
    for (int kk = 0; kk < 4; ++kk)
        kraw[kk] = *(const short8v*)&kls[wv][lr][kk * 32 + lk * 8];

    float ks = 0.f, kss = 0.f;
    #pragma unroll
    for (int kk = 0; kk < 4; ++kk)
        #pragma unroll
        for (int j = 0; j < 8; ++j) { const float f = bf2f(kraw[kk][j]); ks += f; kss += f * f; }
    ks += __shfl_xor(ks, 16); kss += __shfl_xor(kss, 16);
    ks += __shfl_xor(ks, 32); kss += __shfl_xor(kss, 32);
    const float kmu = ks * (1.0f / 128.0f);
    const float krs = rsqrtf(kss * (1.0f / 128.0f) - kmu * kmu + 1e-5f);

    bf16x8 afk[4];
    #pragma unroll
    for (int kk = 0; kk < 4; ++kk) {
        const f32x4 w0 = *(const f32x4*)(lnow + kk * 32 + lk * 8);
        const f32x4 w1 = *(const f32x4*)(lnow + kk * 32 + lk * 8 + 4);
        const f32x4 b0 = *(const f32x4*)(lnob + kk * 32 + lk * 8);
        const f32x4 b1 = *(const f32x4*)(lnob + kk * 32 + lk * 8 + 4);
        short8v o;
        #pragma unroll
        for (int j = 0; j < 4; ++j) {
            o[j]     = f2bf((bf2f(kraw[kk][j])     - kmu) * krs * w0[j] + b0[j]);
            o[4 + j] = f2bf((bf2f(kraw[kk][4 + j]) - kmu) * krs * w1[j] + b1[j]);
        }
        afk[kk] = s2b(o);
    }

    // ---- h = kn @ Wlo^T + blo ; out = gate * h ----
    #pragma unroll
    for (int nt = 0; nt < 8; ++nt) {
        const size_t woff = (size_t)(nt * 16 + lr) * DD + lk * 8;
        f32x4 a0 = {0.f, 0.f, 0.f, 0.f};
        #pragma unroll
        for (int kk = 0; kk < 4; ++kk)
            a0 = __builtin_amdgcn_mfma_f32_16x16x32_bf16(afk[kk], *(const bf16x8*)(wlo_bf + woff + kk * 32), a0, 0, 0, 0);
        const float bl = blo[nt * 16 + lr];
        #pragma unroll
        for (int r = 0; r < 4; ++r) {
            const size_t row = (size_t)batch * NN + row0 + wv * 16 + lk * 4 + r;
            out[row * DD + nt * 16 + lr] = gate[nt][r] * (a0[r] + bl);
        }
    }
}

extern "C" void kernel_launch(void* const* d_in, const int* in_sizes, int n_in,
                              void* d_out, int out_size, void* d_ws, size_t ws_size,
                              hipStream_t stream)
{
    const float* x    = (const float*)d_in[0];
    const float* lnw  = (const float*)d_in[1];
    const float* lnb  = (const float*)d_in[2];
    const float* Wla  = (const float*)d_in[3];
    const float* bla  = (const float*)d_in[4];
    const float* Wga  = (const float*)d_in[5];
    const float* bga  = (const float*)d_in[6];
    const float* Wlb  = (const float*)d_in[7];
    const float* blb  = (const float*)d_in[8];
    const float* Wgb  = (const float*)d_in[9];
    const float* bgb  = (const float*)d_in[10];
    const float* lnow = (const float*)d_in[11];
    const float* lnob = (const float*)d_in[12];
    const float* Wgo  = (const float*)d_in[13];
    const float* bgo  = (const float*)d_in[14];
    const float* Wlo  = (const float*)d_in[15];
    const float* blo  = (const float*)d_in[16];

    float* cbuf = (float*)d_ws;                                      // 4 MB
    short* wbf  = (short*)((char*)d_ws + (size_t)BB * NA * CC * 4);  // 6*32KB
    float* out  = (float*)d_out;

    hipLaunchKernelGGL(kern_wcvt, dim3(WSZ / 256), dim3(256), 0, stream,
                       Wla, Wga, Wlb, Wgb, Wgo, Wlo, wbf);
    hipLaunchKernelGGL(kern_ab, dim3(BB * 512), dim3(64), 0, stream,
                       x, lnw, lnb, wbf, bla, bga, blb, bgb, cbuf);
    hipLaunchKernelGGL(kern_out, dim3(BB * 1024), dim3(256), 0, stream,
                       x, lnw, lnb, lnow, lnob, wbf, bgo, blo, cbuf, out);
}

// Round 5
// 104.429 us; speedup vs baseline: 1.0794x; 1.0794x over previous
//
#include <hip/hip_runtime.h>

// SparsTriangularUpdate — round 5: kill the scratch spills (R4's regression).
//
// Closed form (verified): c[t] = a[:,t*16,:]*b[:,t*16,:];
//   k[:,t*16+s,:] = sum_{m=s+2}^{16} c[:,(t+m)%4096,:]  (s=0..15; s=15 -> 0)
//
// kern_out (barrier-free, wave-private LDS), re-sequenced for register lifetime:
//   x frag-load -> LN(x) 2-shuffle -> afx     (x regs die)
//   15 cbuf loads -> scan -> f32 k in LDS     (cv regs die immediately)
//   gate = sigmoid(xn@Wgo^T) via MFMA
//   k-LN: frag ds_read + 2 shuffles -> afk    (single bf16 rounding)
//   h = kn@Wlo^T via MFMA; out = gate*h
// __launch_bounds__(256) only — R4's (256,4) forced 64 VGPR -> scratch spills
// (FETCH +29MB, WRITE 2x). Peak live ~95 VGPR; let the allocator have them.

#define BB 2
#define NN 65536
#define DD 128
#define CC 128
#define NA 4096
#define STR 16
#define WSZ 16384   // elements per weight matrix

typedef short short8v __attribute__((ext_vector_type(8)));
typedef __bf16 bf16x8 __attribute__((ext_vector_type(8)));
typedef float f32x4 __attribute__((ext_vector_type(4)));
typedef float f32x2 __attribute__((ext_vector_type(2)));

__device__ __forceinline__ float sigf(float v) { return 1.0f / (1.0f + __expf(-v)); }
__device__ __forceinline__ short f2bf(float f) {
    union { float f; unsigned u; } v; v.f = f;
    unsigned r = (v.u + 0x7FFFu + ((v.u >> 16) & 1u)) >> 16;   // RTNE
    return (short)r;
}
__device__ __forceinline__ bf16x8 s2b(short8v s) {
    union { short8v s; bf16x8 b; } u; u.s = s; return u.b;
}

__global__ __launch_bounds__(256)
void kern_wcvt(const float* __restrict__ Wla, const float* __restrict__ Wga,
               const float* __restrict__ Wlb, const float* __restrict__ Wgb,
               const float* __restrict__ Wgo, const float* __restrict__ Wlo,
               short* __restrict__ wbf)
{
    const int i = blockIdx.x * 256 + threadIdx.x;
    wbf[i]           = f2bf(Wla[i]);
    wbf[WSZ + i]     = f2bf(Wga[i]);
    wbf[2 * WSZ + i] = f2bf(Wlb[i]);
    wbf[3 * WSZ + i] = f2bf(Wgb[i]);
    wbf[4 * WSZ + i] = f2bf(Wgo[i]);
    wbf[5 * WSZ + i] = f2bf(Wlo[i]);
}

__global__ __launch_bounds__(64)
void kern_ab(const float* __restrict__ x,
             const float* __restrict__ lnw, const float* __restrict__ lnb,
             const short* __restrict__ wbf,
             const float* __restrict__ bla, const float* __restrict__ bga,
             const float* __restrict__ blb, const float* __restrict__ bgb,
             float* __restrict__ cbuf)
{
    const int l     = threadIdx.x;            // 0..63
    const int bid   = blockIdx.x;             // BB*512
    const int batch = bid >> 9;
    const int t0    = ((bid & 511) >> 1) << 4;
    const int nt0   = (bid & 1) * 4;          // nt half: cols [nt0*16, +64)
    const int lr    = l & 15;
    const int q     = l >> 4;

    const float* xr = x + ((size_t)batch * NN + (size_t)(t0 + lr) * STR) * DD + q * 8;
    f32x4 v[4][2];
    #pragma unroll
    for (int kk = 0; kk < 4; ++kk) {
        v[kk][0] = *(const f32x4*)(xr + kk * 32);
        v[kk][1] = *(const f32x4*)(xr + kk * 32 + 4);
    }
    float s = 0.f, ss = 0.f;
    #pragma unroll
    for (int kk = 0; kk < 4; ++kk)
        #pragma unroll
        for (int h = 0; h < 2; ++h)
            #pragma unroll
            for (int j = 0; j < 4; ++j) { const float f = v[kk][h][j]; s += f; ss += f * f; }
    s += __shfl_xor(s, 16); ss += __shfl_xor(ss, 16);
    s += __shfl_xor(s, 32); ss += __shfl_xor(ss, 32);
    const float mu = s * (1.0f / 128.0f);
    const float rs = rsqrtf(ss * (1.0f / 128.0f) - mu * mu + 1e-5f);

    bf16x8 af[4];
    #pragma unroll
    for (int kk = 0; kk < 4; ++kk) {
        const f32x4 w0 = *(const f32x4*)(lnw + kk * 32 + q * 8);
        const f32x4 w1 = *(const f32x4*)(lnw + kk * 32 + q * 8 + 4);
        const f32x4 b0 = *(const f32x4*)(lnb + kk * 32 + q * 8);
        const f32x4 b1 = *(const f32x4*)(lnb + kk * 32 + q * 8 + 4);
        short8v t;
        #pragma unroll
        for (int j = 0; j < 4; ++j) {
            t[j]     = f2bf((v[kk][0][j] - mu) * rs * w0[j] + b0[j]);
            t[4 + j] = f2bf((v[kk][1][j] - mu) * rs * w1[j] + b1[j]);
        }
        af[kk] = s2b(t);
    }

    const short* wla = wbf;
    const short* wga = wbf + WSZ;
    const short* wlb = wbf + 2 * WSZ;
    const short* wgb = wbf + 3 * WSZ;

    #pragma unroll
    for (int nt = 0; nt < 4; ++nt) {
        const int col = (nt0 + nt) * 16 + lr;
        const size_t woff = (size_t)col * DD + q * 8;
        f32x4 ala = {0.f,0.f,0.f,0.f}, aga = {0.f,0.f,0.f,0.f};
        f32x4 alb = {0.f,0.f,0.f,0.f}, agb = {0.f,0.f,0.f,0.f};
        #pragma unroll
        for (int kk = 0; kk < 4; ++kk) {
            ala = __builtin_amdgcn_mfma_f32_16x16x32_bf16(af[kk], *(const bf16x8*)(wla + woff + kk * 32), ala, 0, 0, 0);
            aga = __builtin_amdgcn_mfma_f32_16x16x32_bf16(af[kk], *(const bf16x8*)(wga + woff + kk * 32), aga, 0, 0, 0);
            alb = __builtin_amdgcn_mfma_f32_16x16x32_bf16(af[kk], *(const bf16x8*)(wlb + woff + kk * 32), alb, 0, 0, 0);
            agb = __builtin_amdgcn_mfma_f32_16x16x32_bf16(af[kk], *(const bf16x8*)(wgb + woff + kk * 32), agb, 0, 0, 0);
        }
        const float xla = bla[col], xga = bga[col], xlb = blb[col], xgb = bgb[col];
        #pragma unroll
        for (int r = 0; r < 4; ++r) {
            const float av = sigf(aga[r] + xga) * (ala[r] + xla);
            const float bv = sigf(agb[r] + xgb) * (alb[r] + xlb);
            cbuf[((size_t)batch * NA + t0 + q * 4 + r) * CC + col] = av * bv;
        }
    }
}

__global__ __launch_bounds__(256)
void kern_out(const float* __restrict__ x,
              const float* __restrict__ lnw,  const float* __restrict__ lnb,
              const float* __restrict__ lnow, const float* __restrict__ lnob,
              const short* __restrict__ wbf,  const float* __restrict__ bgo,
              const float* __restrict__ blo,
              const float* __restrict__ cbuf, float* __restrict__ out)
{
    __shared__ float kls[4][16][132];          // wave-private f32 k tiles
    // chunked XCD swizzle (grid 2048 = 8 XCDs x 256): contiguous ibb per XCD
    // -> neighboring blocks share 14/18 cbuf rows in the same L2.
    const int bid   = blockIdx.x;
    const int swz   = (bid & 7) * 256 + (bid >> 3);
    const int batch = swz >> 10;
    const int ibb   = swz & 1023;
    const int row0  = ibb * 64;
    const int t0    = ibb * 4;

    const int tid = threadIdx.x;
    const int wv = tid >> 6, l = tid & 63;
    const int lr = l & 15, lk = l >> 4;
    const int t  = t0 + wv;

    // ---- x loads in A-fragment layout ----
    const float* xr = x + ((size_t)batch * NN + row0 + wv * 16 + lr) * DD + lk * 8;
    f32x4 v[4][2];
    #pragma unroll
    for (int kk = 0; kk < 4; ++kk) {
        v[kk][0] = *(const f32x4*)(xr + kk * 32);
        v[kk][1] = *(const f32x4*)(xr + kk * 32 + 4);
    }

    // ---- LN(x): 2 shuffles, normalize in-reg -> afx (x regs die here) ----
    float s = 0.f, ss = 0.f;
    #pragma unroll
    for (int kk = 0; kk < 4; ++kk)
        #pragma unroll
        for (int h = 0; h < 2; ++h)
            #pragma unroll
            for (int j = 0; j < 4; ++j) { const float f = v[kk][h][j]; s += f; ss += f * f; }
    s += __shfl_xor(s, 16); ss += __shfl_xor(ss, 16);
    s += __shfl_xor(s, 32); ss += __shfl_xor(ss, 32);
    const float mu = s * (1.0f / 128.0f);
    const float rs = rsqrtf(ss * (1.0f / 128.0f) - mu * mu + 1e-5f);

    bf16x8 afx[4];
    #pragma unroll
    for (int kk = 0; kk < 4; ++kk) {
        const f32x4 w0 = *(const f32x4*)(lnw + kk * 32 + lk * 8);
        const f32x4 w1 = *(const f32x4*)(lnw + kk * 32 + lk * 8 + 4);
        const f32x4 b0 = *(const f32x4*)(lnb + kk * 32 + lk * 8);
        const f32x4 b1 = *(const f32x4*)(lnb + kk * 32 + lk * 8 + 4);
        short8v o;
        #pragma unroll
        for (int j = 0; j < 4; ++j) {
            o[j]     = f2bf((v[kk][0][j] - mu) * rs * w0[j] + b0[j]);
            o[4 + j] = f2bf((v[kk][1][j] - mu) * rs * w1[j] + b1[j]);
        }
        afx[kk] = s2b(o);
    }

    // ---- 15 cbuf loads -> scan -> f32 k in wave-private LDS (cv dies fast) ----
    const int c2 = l * 2;
    {
        f32x2 cv[15];
        #pragma unroll
        for (int sx = 0; sx < 15; ++sx)
            cv[sx] = *(const f32x2*)(cbuf + ((size_t)batch * NA + ((t + sx + 2) & (NA - 1))) * CC + c2);
        f32x2 z = {0.f, 0.f};
        *(f32x2*)&kls[wv][15][c2] = z;
        float s0 = 0.f, s1 = 0.f;
        #pragma unroll
        for (int sx = 14; sx >= 0; --sx) {
            s0 += cv[sx][0]; s1 += cv[sx][1];
            f32x2 o = {s0, s1};
            *(f32x2*)&kls[wv][sx][c2] = o;
        }
    }

    // ---- gate = sigmoid(xn @ Wgo^T + bgo) via MFMA ----
    const short* wgo_bf = wbf + 4 * WSZ;
    const short* wlo_bf = wbf + 5 * WSZ;
    float gate[8][4];
    #pragma unroll
    for (int nt = 0; nt < 8; ++nt) {
        const size_t woff = (size_t)(nt * 16 + lr) * DD + lk * 8;
        f32x4 a0 = {0.f, 0.f, 0.f, 0.f};
        #pragma unroll
        for (int kk = 0; kk < 4; ++kk)
            a0 = __builtin_amdgcn_mfma_f32_16x16x32_bf16(afx[kk], *(const bf16x8*)(wgo_bf + woff + kk * 32), a0, 0, 0, 0);
        const float bg = bgo[nt * 16 + lr];
        #pragma unroll
        for (int r = 0; r < 4; ++r) gate[nt][r] = sigf(a0[r] + bg);
    }

    // ---- k-LN: fragment-layout f32 read, 2 shuffles, single bf16 round ----
    f32x4 kr[4][2];
    #pragma unroll
    for (int kk = 0; kk < 4; ++kk) {
        kr[kk][0] = *(const f32x4*)&kls[wv][lr][kk * 32 + lk * 8];
        kr[kk][1] = *(const f32x4*)&kls[wv][lr][kk * 32 + lk * 8 + 4];
    }
    float ks = 0.f, kss = 0.f;
    #pragma unroll
    for (int kk = 0; kk < 4; ++kk)
        #pragma unroll
        for (int h = 0; h < 2; ++h)
            #pragma unroll
            for (int j = 0; j < 4; ++j) { const float f = kr[kk][h][j]; ks += f; kss += f * f; }
    ks += __shfl_xor(ks, 16); kss += __shfl_xor(kss, 16);
    ks += __shfl_xor(ks, 32); kss += __shfl_xor(kss, 32);
    const float kmu = ks * (1.0f / 128.0f);
    const float krs = rsqrtf(kss * (1.0f / 128.0f) - kmu * kmu + 1e-5f);

    bf16x8 afk[4];
    #pragma unroll
    for (int kk = 0; kk < 4; ++kk) {
        const f32x4 w0 = *(const f32x4*)(lnow + kk * 32 + lk * 8);
        const f32x4 w1 = *(const f32x4*)(lnow + kk * 32 + lk * 8 + 4);
        const f32x4 b0 = *(const f32x4*)(lnob + kk * 32 + lk * 8);
        const f32x4 b1 = *(const f32x4*)(lnob + kk * 32 + lk * 8 + 4);
        short8v o;
        #pragma unroll
        for (int j = 0; j < 4; ++j) {
            o[j]     = f2bf((kr[kk][0][j] - kmu) * krs * w0[j] + b0[j]);
            o[4 + j] = f2bf((kr[kk][1][j] - kmu) * krs * w1[j] + b1[j]);
        }
        afk[kk] = s2b(o);
    }

    // ---- h = kn @ Wlo^T + blo ; out = gate * h ----
    #pragma unroll
    for (int nt = 0; nt < 8; ++nt) {
        const size_t woff = (size_t)(nt * 16 + lr) * DD + lk * 8;
        f32x4 a0 = {0.f, 0.f, 0.f, 0.f};
        #pragma unroll
        for (int kk = 0; kk < 4; ++kk)
            a0 = __builtin_amdgcn_mfma_f32_16x16x32_bf16(afk[kk], *(const bf16x8*)(wlo_bf + woff + kk * 32), a0, 0, 0, 0);
        const float bl = blo[nt * 16 + lr];
        #pragma unroll
        for (int r = 0; r < 4; ++r) {
            const size_t row = (size_t)batch * NN + row0 + wv * 16 + lk * 4 + r;
            out[row * DD + nt * 16 + lr] = gate[nt][r] * (a0[r] + bl);
        }
    }
}

extern "C" void kernel_launch(void* const* d_in, const int* in_sizes, int n_in,
                              void* d_out, int out_size, void* d_ws, size_t ws_size,
                              hipStream_t stream)
{
    const float* x    = (const float*)d_in[0];
    const float* lnw  = (const float*)d_in[1];
    const float* lnb  = (const float*)d_in[2];
    const float* Wla  = (const float*)d_in[3];
    const float* bla  = (const float*)d_in[4];
    const float* Wga  = (const float*)d_in[5];
    const float* bga  = (const float*)d_in[6];
    const float* Wlb  = (const float*)d_in[7];
    const float* blb  = (const float*)d_in[8];
    const float* Wgb  = (const float*)d_in[9];
    const float* bgb  = (const float*)d_in[10];
    const float* lnow = (const float*)d_in[11];
    const float* lnob = (const float*)d_in[12];
    const float* Wgo  = (const float*)d_in[13];
    const float* bgo  = (const float*)d_in[14];
    const float* Wlo  = (const float*)d_in[15];
    const float* blo  = (const float*)d_in[16];

    float* cbuf = (float*)d_ws;                                      // 4 MB
    short* wbf  = (short*)((char*)d_ws + (size_t)BB * NA * CC * 4);  // 6*32KB
    float* out  = (float*)d_out;

    hipLaunchKernelGGL(kern_wcvt, dim3(WSZ / 256), dim3(256), 0, stream,
                       Wla, Wga, Wlb, Wgb, Wgo, Wlo, wbf);
    hipLaunchKernelGGL(kern_ab, dim3(BB * 512), dim3(64), 0, stream,
                       x, lnw, lnb, wbf, bla, bga, blb, bgb, cbuf);
    hipLaunchKernelGGL(kern_out, dim3(BB * 1024), dim3(256), 0, stream,
                       x, lnw, lnb, lnow, lnob, wbf, bgo, blo, cbuf, out);
}

// Round 6
// 57.774 us; speedup vs baseline: 1.9511x; 1.8076x over previous
//
#include <hip/hip_runtime.h>

// SparsTriangularUpdate — round 6: fix the weight-fragment path.
//
// Closed form (verified): c[t] = a[:,t*16,:]*b[:,t*16,:];
//   k[:,t*16+s,:] = sum_{m=s+2}^{16} c[:,(t+m)%4096,:]  (s=0..15; s=15 -> 0)
//
// R5 post-mortem: per-MFMA weight loads gathered 16 distinct 256B lines per
// instruction (lanes stride 256B) and each wave pulled 64KB of fragments for
// only 16 rows -> 512MB L2 traffic + serialized TA -> latency-bound at 20%
// occupancy. R6: (1) weights stored in FRAGMENT ORDER (lane l reads base+l*8,
// 1KB coalesced per load); (2) each wave covers 32 rows (2 t-groups) and the
// gate/h GEMMs fuse into one nt loop sharing B-fragments -> weight bytes /2,
// nothing persists but afx/afk; (3) barrier-free waves, bf16 k in LDS.

#define BB 2
#define NN 65536
#define DD 128
#define CC 128
#define NA 4096
#define STR 16
#define WSZ 16384   // elements per weight matrix

typedef short short4v __attribute__((ext_vector_type(4)));
typedef short short8v __attribute__((ext_vector_type(8)));
typedef __bf16 bf16x8 __attribute__((ext_vector_type(8)));
typedef float f32x4 __attribute__((ext_vector_type(4)));
typedef float f32x2 __attribute__((ext_vector_type(2)));

__device__ __forceinline__ float sigf(float v) { return 1.0f / (1.0f + __expf(-v)); }
__device__ __forceinline__ short f2bf(float f) {
    union { float f; unsigned u; } v; v.f = f;
    unsigned r = (v.u + 0x7FFFu + ((v.u >> 16) & 1u)) >> 16;   // RTNE
    return (short)r;
}
__device__ __forceinline__ float bf2f(short b) {
    union { unsigned u; float f; } v; v.u = ((unsigned)(unsigned short)b) << 16;
    return v.f;
}
__device__ __forceinline__ bf16x8 s2b(short8v s) {
    union { short8v s; bf16x8 b; } u; u.s = s; return u.b;
}

// Fragment order: element (ch, d) -> pos = ((ch>>4)*4 + (d>>5))*512 +
//   (((d>>3)&3)*16 + (ch&15))*8 + (d&7).  Lane l (=lk*16+lr) then reads its
// bf16x8 for tile (nt,kk) at wptr + (nt*4+kk)*512 + l*8 — fully coalesced.
__global__ __launch_bounds__(256)
void kern_wcvt(const float* __restrict__ Wla, const float* __restrict__ Wga,
               const float* __restrict__ Wlb, const float* __restrict__ Wgb,
               const float* __restrict__ Wgo, const float* __restrict__ Wlo,
               short* __restrict__ wbf)
{
    const int i  = blockIdx.x * 256 + threadIdx.x;
    const int ch = i >> 7, d = i & 127;
    const int pos = ((ch >> 4) * 4 + (d >> 5)) * 512
                  + ((((d >> 3) & 3) * 16 + (ch & 15)) * 8) + (d & 7);
    wbf[pos]           = f2bf(Wla[i]);
    wbf[WSZ + pos]     = f2bf(Wga[i]);
    wbf[2 * WSZ + pos] = f2bf(Wlb[i]);
    wbf[3 * WSZ + pos] = f2bf(Wgb[i]);
    wbf[4 * WSZ + pos] = f2bf(Wgo[i]);
    wbf[5 * WSZ + pos] = f2bf(Wlo[i]);
}

__global__ __launch_bounds__(64)
void kern_ab(const float* __restrict__ x,
             const float* __restrict__ lnw, const float* __restrict__ lnb,
             const short* __restrict__ wbf,
             const float* __restrict__ bla, const float* __restrict__ bga,
             const float* __restrict__ blb, const float* __restrict__ bgb,
             float* __restrict__ cbuf)
{
    const int l     = threadIdx.x;            // 0..63
    const int bid   = blockIdx.x;             // BB*512
    const int batch = bid >> 9;
    const int t0    = ((bid & 511) >> 1) << 4;
    const int nt0   = (bid & 1) * 4;          // nt half: cols [nt0*16, +64)
    const int lr    = l & 15;
    const int q     = l >> 4;
    const int fl    = l * 8;                  // fragment-order lane offset

    const float* xr = x + ((size_t)batch * NN + (size_t)(t0 + lr) * STR) * DD + q * 8;
    f32x4 v[4][2];
    #pragma unroll
    for (int kk = 0; kk < 4; ++kk) {
        v[kk][0] = *(const f32x4*)(xr + kk * 32);
        v[kk][1] = *(const f32x4*)(xr + kk * 32 + 4);
    }
    float s = 0.f, ss = 0.f;
    #pragma unroll
    for (int kk = 0; kk < 4; ++kk)
        #pragma unroll
        for (int h = 0; h < 2; ++h)
            #pragma unroll
            for (int j = 0; j < 4; ++j) { const float f = v[kk][h][j]; s += f; ss += f * f; }
    s += __shfl_xor(s, 16); ss += __shfl_xor(ss, 16);
    s += __shfl_xor(s, 32); ss += __shfl_xor(ss, 32);
    const float mu = s * (1.0f / 128.0f);
    const float rs = rsqrtf(ss * (1.0f / 128.0f) - mu * mu + 1e-5f);

    bf16x8 af[4];
    #pragma unroll
    for (int kk = 0; kk < 4; ++kk) {
        const f32x4 w0 = *(const f32x4*)(lnw + kk * 32 + q * 8);
        const f32x4 w1 = *(const f32x4*)(lnw + kk * 32 + q * 8 + 4);
        const f32x4 b0 = *(const f32x4*)(lnb + kk * 32 + q * 8);
        const f32x4 b1 = *(const f32x4*)(lnb + kk * 32 + q * 8 + 4);
        short8v t;
        #pragma unroll
        for (int j = 0; j < 4; ++j) {
            t[j]     = f2bf((v[kk][0][j] - mu) * rs * w0[j] + b0[j]);
            t[4 + j] = f2bf((v[kk][1][j] - mu) * rs * w1[j] + b1[j]);
        }
        af[kk] = s2b(t);
    }

    const short* wla = wbf;
    const short* wga = wbf + WSZ;
    const short* wlb = wbf + 2 * WSZ;
    const short* wgb = wbf + 3 * WSZ;

    #pragma unroll
    for (int nt = 0; nt < 4; ++nt) {
        const int col  = (nt0 + nt) * 16 + lr;
        const int base = ((nt0 + nt) * 4) * 512 + fl;
        f32x4 ala = {0.f,0.f,0.f,0.f}, aga = {0.f,0.f,0.f,0.f};
        f32x4 alb = {0.f,0.f,0.f,0.f}, agb = {0.f,0.f,0.f,0.f};
        #pragma unroll
        for (int kk = 0; kk < 4; ++kk) {
            const int o = base + kk * 512;
            ala = __builtin_amdgcn_mfma_f32_16x16x32_bf16(af[kk], *(const bf16x8*)(wla + o), ala, 0, 0, 0);
            aga = __builtin_amdgcn_mfma_f32_16x16x32_bf16(af[kk], *(const bf16x8*)(wga + o), aga, 0, 0, 0);
            alb = __builtin_amdgcn_mfma_f32_16x16x32_bf16(af[kk], *(const bf16x8*)(wlb + o), alb, 0, 0, 0);
            agb = __builtin_amdgcn_mfma_f32_16x16x32_bf16(af[kk], *(const bf16x8*)(wgb + o), agb, 0, 0, 0);
        }
        const float xla = bla[col], xga = bga[col], xlb = blb[col], xgb = bgb[col];
        #pragma unroll
        for (int r = 0; r < 4; ++r) {
            const float av = sigf(aga[r] + xga) * (ala[r] + xla);
            const float bv = sigf(agb[r] + xgb) * (alb[r] + xlb);
            cbuf[((size_t)batch * NA + t0 + q * 4 + r) * CC + col] = av * bv;
        }
    }
}

__global__ __launch_bounds__(256)
void kern_out(const float* __restrict__ x,
              const float* __restrict__ lnw,  const float* __restrict__ lnb,
              const float* __restrict__ lnow, const float* __restrict__ lnob,
              const short* __restrict__ wbf,  const float* __restrict__ bgo,
              const float* __restrict__ blo,
              const float* __restrict__ cbuf, float* __restrict__ out)
{
    __shared__ short kls[4][2][16][136];       // wave-private bf16 k tiles (34 KB)
    // chunked XCD swizzle (grid 1024 = 8 x 128, bijective)
    const int bid   = blockIdx.x;
    const int swz   = (bid & 7) * 128 + (bid >> 3);
    const int batch = swz >> 9;                // 512 blocks per batch
    const int ibb   = swz & 511;
    const int row0  = ibb * 128;               // 128 rows per block
    const int t0    = ibb * 8;                 // 8 t-groups per block

    const int tid = threadIdx.x;
    const int wv = tid >> 6, l = tid & 63;
    const int lr = l & 15, lk = l >> 4;
    const int fl = l * 8;                      // fragment-order lane offset

    // ---- LN(x) -> afx for both groups (2 shuffles each, no LDS) ----
    bf16x8 afx[2][4];
    #pragma unroll
    for (int g = 0; g < 2; ++g) {
        const float* xr = x + ((size_t)batch * NN + row0 + (wv * 2 + g) * 16 + lr) * DD + lk * 8;
        f32x4 v[4][2];
        #pragma unroll
        for (int kk = 0; kk < 4; ++kk) {
            v[kk][0] = *(const f32x4*)(xr + kk * 32);
            v[kk][1] = *(const f32x4*)(xr + kk * 32 + 4);
        }
        float s = 0.f, ss = 0.f;
        #pragma unroll
        for (int kk = 0; kk < 4; ++kk)
            #pragma unroll
            for (int h = 0; h < 2; ++h)
                #pragma unroll
                for (int j = 0; j < 4; ++j) { const float f = v[kk][h][j]; s += f; ss += f * f; }
        s += __shfl_xor(s, 16); ss += __shfl_xor(ss, 16);
        s += __shfl_xor(s, 32); ss += __shfl_xor(ss, 32);
        const float mu = s * (1.0f / 128.0f);
        const float rs = rsqrtf(ss * (1.0f / 128.0f) - mu * mu + 1e-5f);
        #pragma unroll
        for (int kk = 0; kk < 4; ++kk) {
            const f32x4 w0 = *(const f32x4*)(lnw + kk * 32 + lk * 8);
            const f32x4 w1 = *(const f32x4*)(lnw + kk * 32 + lk * 8 + 4);
            const f32x4 b0 = *(const f32x4*)(lnb + kk * 32 + lk * 8);
            const f32x4 b1 = *(const f32x4*)(lnb + kk * 32 + lk * 8 + 4);
            short8v o;
            #pragma unroll
            for (int j = 0; j < 4; ++j) {
                o[j]     = f2bf((v[kk][0][j] - mu) * rs * w0[j] + b0[j]);
                o[4 + j] = f2bf((v[kk][1][j] - mu) * rs * w1[j] + b1[j]);
            }
            afx[g][kk] = s2b(o);
        }
    }

    // ---- scan: lane-halves split the 2 groups; 15 f32x4 loads, bf16 k ----
    {
        const int sg = l >> 5;                 // group this lane scans
        const int c4 = (l & 31) * 4;
        const int t  = t0 + wv * 2 + sg;
        f32x4 cv[15];
        #pragma unroll
        for (int sx = 0; sx < 15; ++sx)
            cv[sx] = *(const f32x4*)(cbuf + ((size_t)batch * NA + ((t + sx + 2) & (NA - 1))) * CC + c4);
        short4v z = {0, 0, 0, 0};
        *(short4v*)&kls[wv][sg][15][c4] = z;
        float s0 = 0.f, s1 = 0.f, s2 = 0.f, s3 = 0.f;
        #pragma unroll
        for (int sx = 14; sx >= 0; --sx) {
            s0 += cv[sx][0]; s1 += cv[sx][1]; s2 += cv[sx][2]; s3 += cv[sx][3];
            short4v o; o[0] = f2bf(s0); o[1] = f2bf(s1); o[2] = f2bf(s2); o[3] = f2bf(s3);
            *(short4v*)&kls[wv][sg][sx][c4] = o;
        }
    }

    // ---- k-LN -> afk for both groups ----
    bf16x8 afk[2][4];
    #pragma unroll
    for (int g = 0; g < 2; ++g) {
        short8v kraw[4];
        #pragma unroll
        for (int kk = 0; kk < 4; ++kk)
            kraw[kk] = *(const short8v*)&kls[wv][g][lr][kk * 32 + lk * 8];
        float ks = 0.f, kss = 0.f;
        #pragma unroll
        for (int kk = 0; kk < 4; ++kk)
            #pragma unroll
            for (int j = 0; j < 8; ++j) { const float f = bf2f(kraw[kk][j]); ks += f; kss += f * f; }
        ks += __shfl_xor(ks, 16); kss += __shfl_xor(kss, 16);
        ks += __shfl_xor(ks, 32); kss += __shfl_xor(kss, 32);
        const float kmu = ks * (1.0f / 128.0f);
        const float krs = rsqrtf(kss * (1.0f / 128.0f) - kmu * kmu + 1e-5f);
        #pragma unroll
        for (int kk = 0; kk < 4; ++kk) {
            const f32x4 w0 = *(const f32x4*)(lnow + kk * 32 + lk * 8);
            const f32x4 w1 = *(const f32x4*)(lnow + kk * 32 + lk * 8 + 4);
            const f32x4 b0 = *(const f32x4*)(lnob + kk * 32 + lk * 8);
            const f32x4 b1 = *(const f32x4*)(lnob + kk * 32 + lk * 8 + 4);
            short8v o;
            #pragma unroll
            for (int j = 0; j < 4; ++j) {
                o[j]     = f2bf((bf2f(kraw[kk][j])     - kmu) * krs * w0[j] + b0[j]);
                o[4 + j] = f2bf((bf2f(kraw[kk][4 + j]) - kmu) * krs * w1[j] + b1[j]);
            }
            afk[g][kk] = s2b(o);
        }
    }

    // ---- fused gate+h GEMMs: B-frags shared by 2 groups x 2 GEMMs ----
    const short* wgo = wbf + 4 * WSZ;
    const short* wlo = wbf + 5 * WSZ;
    #pragma unroll
    for (int nt = 0; nt < 8; ++nt) {
        bf16x8 bg_[4], bh_[4];
        #pragma unroll
        for (int kk = 0; kk < 4; ++kk) {
            bg_[kk] = *(const bf16x8*)(wgo + (nt * 4 + kk) * 512 + fl);
            bh_[kk] = *(const bf16x8*)(wlo + (nt * 4 + kk) * 512 + fl);
        }
        f32x4 ag0 = {0.f,0.f,0.f,0.f}, ag1 = {0.f,0.f,0.f,0.f};
        f32x4 ah0 = {0.f,0.f,0.f,0.f}, ah1 = {0.f,0.f,0.f,0.f};
        #pragma unroll
        for (int kk = 0; kk < 4; ++kk) {
            ag0 = __builtin_amdgcn_mfma_f32_16x16x32_bf16(afx[0][kk], bg_[kk], ag0, 0, 0, 0);
            ag1 = __builtin_amdgcn_mfma_f32_16x16x32_bf16(afx[1][kk], bg_[kk], ag1, 0, 0, 0);
            ah0 = __builtin_amdgcn_mfma_f32_16x16x32_bf16(afk[0][kk], bh_[kk], ah0, 0, 0, 0);
            ah1 = __builtin_amdgcn_mfma_f32_16x16x32_bf16(afk[1][kk], bh_[kk], ah1, 0, 0, 0);
        }
        const float bgv = bgo[nt * 16 + lr];
        const float blv = blo[nt * 16 + lr];
        #pragma unroll
        for (int r = 0; r < 4; ++r) {
            const size_t rowa = (size_t)batch * NN + row0 + wv * 32 + lk * 4 + r;
            out[rowa * DD + nt * 16 + lr]        = sigf(ag0[r] + bgv) * (ah0[r] + blv);
            out[(rowa + 16) * DD + nt * 16 + lr] = sigf(ag1[r] + bgv) * (ah1[r] + blv);
        }
    }
}

extern "C" void kernel_launch(void* const* d_in, const int* in_sizes, int n_in,
                              void* d_out, int out_size, void* d_ws, size_t ws_size,
                              hipStream_t stream)
{
    const float* x    = (const float*)d_in[0];
    const float* lnw  = (const float*)d_in[1];
    const float* lnb  = (const float*)d_in[2];
    const float* Wla  = (const float*)d_in[3];
    const float* bla  = (const float*)d_in[4];
    const float* Wga  = (const float*)d_in[5];
    const float* bga  = (const float*)d_in[6];
    const float* Wlb  = (const float*)d_in[7];
    const float* blb  = (const float*)d_in[8];
    const float* Wgb  = (const float*)d_in[9];
    const float* bgb  = (const float*)d_in[10];
    const float* lnow = (const float*)d_in[11];
    const float* lnob = (const float*)d_in[12];
    const float* Wgo  = (const float*)d_in[13];
    const float* bgo  = (const float*)d_in[14];
    const float* Wlo  = (const float*)d_in[15];
    const float* blo  = (const float*)d_in[16];

    float* cbuf = (float*)d_ws;                                      // 4 MB
    short* wbf  = (short*)((char*)d_ws + (size_t)BB * NA * CC * 4);  // 6*32KB
    float* out  = (float*)d_out;

    hipLaunchKernelGGL(kern_wcvt, dim3(WSZ / 256), dim3(256), 0, stream,
                       Wla, Wga, Wlb, Wgb, Wgo, Wlo, wbf);
    hipLaunchKernelGGL(kern_ab, dim3(BB * 512), dim3(64), 0, stream,
                       x, lnw, lnb, wbf, bla, bga, blb, bgb, cbuf);
    hipLaunchKernelGGL(kern_out, dim3(BB * 512), dim3(256), 0, stream,
                       x, lnw, lnb, lnow, lnob, wbf, bgo, blo, cbuf, out);
}

// Round 7
// 51.724 us; speedup vs baseline: 2.1793x; 1.1170x over previous
//
#include <hip/hip_runtime.h>

// SparsTriangularUpdate — round 7: LN algebraic fold + native bf16 + 1-wave blocks.
//
// Closed form (verified): c[t] = a[:,t*16,:]*b[:,t*16,:];
//   k[:,t*16+s,:] = sum_{m=s+2}^{16} c[:,(t+m)%4096,:]  (s=0..15; s=15 -> 0)
//
// LN fold: LN(x)@W^T = [(x-mu)*rs] @ (W o w)^T + (W.b + bias)
//   -> weights stored as bf16(W*w) in fragment order; v = W.b + bias precomputed.
//   Per-element normalize = 1 FMA; epilogue = 1 add (replaces old bias add).
// kern_out: 1 wave (64 thr) per 32 rows, LDS 8.7KB wave-private, barrier-free.

#define BB 2
#define NN 65536
#define DD 128
#define CC 128
#define NA 4096
#define STR 16
#define WSZ 16384   // elements per weight matrix

typedef short short4v __attribute__((ext_vector_type(4)));
typedef short short8v __attribute__((ext_vector_type(8)));
typedef __bf16 bf16x8 __attribute__((ext_vector_type(8)));
typedef float f32x4 __attribute__((ext_vector_type(4)));

__device__ __forceinline__ float sigf(float v) { return 1.0f / (1.0f + __expf(-v)); }
__device__ __forceinline__ short nbf(float f) {           // native RTNE f32->bf16
    union { __bf16 h; short s; } u; u.h = (__bf16)f; return u.s;
}
__device__ __forceinline__ float bf2f(short b) {
    union { unsigned u; float f; } v; v.u = ((unsigned)(unsigned short)b) << 16;
    return v.f;
}
__device__ __forceinline__ bf16x8 s2b(short8v s) {
    union { short8v s; bf16x8 b; } u; u.s = s; return u.b;
}

// Fragment order: element (ch,d) -> pos = ((ch>>4)*4 + (d>>5))*512 +
//   (((d>>3)&3)*16 + (ch&15))*8 + (d&7). Lane l reads tile (nt,kk) at
//   wptr + (nt*4+kk)*512 + l*8 — fully coalesced 1KB per wave-load.
__global__ __launch_bounds__(256)
void kern_wcvt(const float* __restrict__ Wla, const float* __restrict__ Wga,
               const float* __restrict__ Wlb, const float* __restrict__ Wgb,
               const float* __restrict__ Wgo, const float* __restrict__ Wlo,
               const float* __restrict__ lnw, const float* __restrict__ lnb,
               const float* __restrict__ lnow, const float* __restrict__ lnob,
               const float* __restrict__ bla, const float* __restrict__ bga,
               const float* __restrict__ blb, const float* __restrict__ bgb,
               const float* __restrict__ bgo, const float* __restrict__ blo,
               short* __restrict__ wbf, float* __restrict__ vtab)
{
    const int b = blockIdx.x;
    if (b < 64) {
        // convert + fold LN weight into W (columns scaled by w_d)
        const int i  = b * 256 + threadIdx.x;
        const int ch = i >> 7, d = i & 127;
        const int pos = ((ch >> 4) * 4 + (d >> 5)) * 512
                      + ((((d >> 3) & 3) * 16 + (ch & 15)) * 8) + (d & 7);
        const float wi = lnw[d], wo = lnow[d];
        wbf[pos]           = nbf(Wla[i] * wi);
        wbf[WSZ + pos]     = nbf(Wga[i] * wi);
        wbf[2 * WSZ + pos] = nbf(Wlb[i] * wi);
        wbf[3 * WSZ + pos] = nbf(Wgb[i] * wi);
        wbf[4 * WSZ + pos] = nbf(Wgo[i] * wi);
        wbf[5 * WSZ + pos] = nbf(Wlo[i] * wo);
    } else {
        // v_m[c] = sum_d W_m[c,d]*b_m[d] + bias_m[c]   (m = 0..5)
        const int t = (b - 64) * 256 + threadIdx.x;     // 0..767
        const int m = t >> 7, c = t & 127;
        const float* Wr = (m == 0) ? Wla : (m == 1) ? Wga : (m == 2) ? Wlb
                        : (m == 3) ? Wgb : (m == 4) ? Wgo : Wlo;
        const float* bb = (m == 5) ? lnob : lnb;
        const float* bi = (m == 0) ? bla : (m == 1) ? bga : (m == 2) ? blb
                        : (m == 3) ? bgb : (m == 4) ? bgo : blo;
        const float* row = Wr + (size_t)c * DD;
        float acc = 0.f;
        for (int d = 0; d < DD; d += 4) {
            const f32x4 w4 = *(const f32x4*)(row + d);
            const f32x4 b4 = *(const f32x4*)(bb + d);
            acc += w4[0]*b4[0] + w4[1]*b4[1] + w4[2]*b4[2] + w4[3]*b4[3];
        }
        vtab[m * 128 + c] = acc + bi[c];
    }
}

__global__ __launch_bounds__(64)
void kern_ab(const float* __restrict__ x, const short* __restrict__ wbf,
             const float* __restrict__ vtab, float* __restrict__ cbuf)
{
    const int l     = threadIdx.x;            // 0..63
    const int bid   = blockIdx.x;             // BB*512
    const int batch = bid >> 9;
    const int t0    = ((bid & 511) >> 1) << 4;
    const int nt0   = (bid & 1) * 4;          // nt half: cols [nt0*16, +64)
    const int lr    = l & 15;
    const int q     = l >> 4;
    const int fl    = l * 8;

    const float* xr = x + ((size_t)batch * NN + (size_t)(t0 + lr) * STR) * DD + q * 8;
    f32x4 v[4][2];
    #pragma unroll
    for (int kk = 0; kk < 4; ++kk) {
        v[kk][0] = *(const f32x4*)(xr + kk * 32);
        v[kk][1] = *(const f32x4*)(xr + kk * 32 + 4);
    }
    float s = 0.f, ss = 0.f;
    #pragma unroll
    for (int kk = 0; kk < 4; ++kk)
        #pragma unroll
        for (int h = 0; h < 2; ++h)
            #pragma unroll
            for (int j = 0; j < 4; ++j) { const float f = v[kk][h][j]; s += f; ss += f * f; }
    s += __shfl_xor(s, 16); ss += __shfl_xor(ss, 16);
    s += __shfl_xor(s, 32); ss += __shfl_xor(ss, 32);
    const float mu = s * (1.0f / 128.0f);
    const float rs = rsqrtf(ss * (1.0f / 128.0f) - mu * mu + 1e-5f);
    const float p  = -mu * rs;

    bf16x8 af[4];
    #pragma unroll
    for (int kk = 0; kk < 4; ++kk) {
        short8v t;
        #pragma unroll
        for (int j = 0; j < 4; ++j) {
            t[j]     = nbf(v[kk][0][j] * rs + p);
            t[4 + j] = nbf(v[kk][1][j] * rs + p);
        }
        af[kk] = s2b(t);
    }

    const short* wla = wbf;
    const short* wga = wbf + WSZ;
    const short* wlb = wbf + 2 * WSZ;
    const short* wgb = wbf + 3 * WSZ;

    #pragma unroll
    for (int nt = 0; nt < 4; ++nt) {
        const int col  = (nt0 + nt) * 16 + lr;
        const int base = ((nt0 + nt) * 4) * 512 + fl;
        f32x4 ala = {0.f,0.f,0.f,0.f}, aga = {0.f,0.f,0.f,0.f};
        f32x4 alb = {0.f,0.f,0.f,0.f}, agb = {0.f,0.f,0.f,0.f};
        #pragma unroll
        for (int kk = 0; kk < 4; ++kk) {
            const int o = base + kk * 512;
            ala = __builtin_amdgcn_mfma_f32_16x16x32_bf16(af[kk], *(const bf16x8*)(wla + o), ala, 0, 0, 0);
            aga = __builtin_amdgcn_mfma_f32_16x16x32_bf16(af[kk], *(const bf16x8*)(wga + o), aga, 0, 0, 0);
            alb = __builtin_amdgcn_mfma_f32_16x16x32_bf16(af[kk], *(const bf16x8*)(wlb + o), alb, 0, 0, 0);
            agb = __builtin_amdgcn_mfma_f32_16x16x32_bf16(af[kk], *(const bf16x8*)(wgb + o), agb, 0, 0, 0);
        }
        const float vla = vtab[col], vga = vtab[128 + col];
        const float vlb = vtab[256 + col], vgb = vtab[384 + col];
        #pragma unroll
        for (int r = 0; r < 4; ++r) {
            const float av = sigf(aga[r] + vga) * (ala[r] + vla);
            const float bv = sigf(agb[r] + vgb) * (alb[r] + vlb);
            cbuf[((size_t)batch * NA + t0 + q * 4 + r) * CC + col] = av * bv;
        }
    }
}

__global__ __launch_bounds__(64)
void kern_out(const float* __restrict__ x, const short* __restrict__ wbf,
              const float* __restrict__ vtab, const float* __restrict__ cbuf,
              float* __restrict__ out)
{
    __shared__ short kls[2][16][136];          // wave-private bf16 k tiles (8.7 KB)
    // chunked XCD swizzle (grid 4096 = 8 x 512, bijective)
    const int bid   = blockIdx.x;
    const int swz   = (bid & 7) * 512 + (bid >> 3);
    const int batch = swz >> 11;               // 2048 blocks per batch
    const int ib    = swz & 2047;
    const int row0  = ib * 32;                 // 32 rows per block (1 wave)
    const int t0    = ib * 2;

    const int l  = threadIdx.x;
    const int lr = l & 15, lk = l >> 4;
    const int fl = l * 8;

    // ---- LN(x) -> afx for both groups: stats + 1 FMA/elem (fold) ----
    bf16x8 afx[2][4];
    #pragma unroll
    for (int g = 0; g < 2; ++g) {
        const float* xr = x + ((size_t)batch * NN + row0 + g * 16 + lr) * DD + lk * 8;
        f32x4 v[4][2];
        #pragma unroll
        for (int kk = 0; kk < 4; ++kk) {
            v[kk][0] = *(const f32x4*)(xr + kk * 32);
            v[kk][1] = *(const f32x4*)(xr + kk * 32 + 4);
        }
        float s = 0.f, ss = 0.f;
        #pragma unroll
        for (int kk = 0; kk < 4; ++kk)
            #pragma unroll
            for (int h = 0; h < 2; ++h)
                #pragma unroll
                for (int j = 0; j < 4; ++j) { const float f = v[kk][h][j]; s += f; ss += f * f; }
        s += __shfl_xor(s, 16); ss += __shfl_xor(ss, 16);
        s += __shfl_xor(s, 32); ss += __shfl_xor(ss, 32);
        const float mu = s * (1.0f / 128.0f);
        const float rs = rsqrtf(ss * (1.0f / 128.0f) - mu * mu + 1e-5f);
        const float p  = -mu * rs;
        #pragma unroll
        for (int kk = 0; kk < 4; ++kk) {
            short8v o;
            #pragma unroll
            for (int j = 0; j < 4; ++j) {
                o[j]     = nbf(v[kk][0][j] * rs + p);
                o[4 + j] = nbf(v[kk][1][j] * rs + p);
            }
            afx[g][kk] = s2b(o);
        }
    }

    // ---- scan: lane-halves split the 2 groups; raw bf16 k -> LDS ----
    {
        const int sg = l >> 5;
        const int c4 = (l & 31) * 4;
        const int t  = t0 + sg;
        f32x4 cv[15];
        #pragma unroll
        for (int sx = 0; sx < 15; ++sx)
            cv[sx] = *(const f32x4*)(cbuf + ((size_t)batch * NA + ((t + sx + 2) & (NA - 1))) * CC + c4);
        short4v z = {0, 0, 0, 0};
        *(short4v*)&kls[sg][15][c4] = z;
        float s0 = 0.f, s1 = 0.f, s2 = 0.f, s3 = 0.f;
        #pragma unroll
        for (int sx = 14; sx >= 0; --sx) {
            s0 += cv[sx][0]; s1 += cv[sx][1]; s2 += cv[sx][2]; s3 += cv[sx][3];
            short4v o; o[0] = nbf(s0); o[1] = nbf(s1); o[2] = nbf(s2); o[3] = nbf(s3);
            *(short4v*)&kls[sg][sx][c4] = o;
        }
    }

    // ---- k-LN -> afk: frag read, stats, 1 FMA/elem (fold) ----
    bf16x8 afk[2][4];
    #pragma unroll
    for (int g = 0; g < 2; ++g) {
        short8v kraw[4];
        #pragma unroll
        for (int kk = 0; kk < 4; ++kk)
            kraw[kk] = *(const short8v*)&kls[g][lr][kk * 32 + lk * 8];
        float ks = 0.f, kss = 0.f;
        #pragma unroll
        for (int kk = 0; kk < 4; ++kk)
            #pragma unroll
            for (int j = 0; j < 8; ++j) { const float f = bf2f(kraw[kk][j]); ks += f; kss += f * f; }
        ks += __shfl_xor(ks, 16); kss += __shfl_xor(kss, 16);
        ks += __shfl_xor(ks, 32); kss += __shfl_xor(kss, 32);
        const float kmu = ks * (1.0f / 128.0f);
        const float krs = rsqrtf(kss * (1.0f / 128.0f) - kmu * kmu + 1e-5f);
        const float kp  = -kmu * krs;
        #pragma unroll
        for (int kk = 0; kk < 4; ++kk) {
            short8v o;
            #pragma unroll
            for (int j = 0; j < 8; ++j)
                o[j] = nbf(bf2f(kraw[kk][j]) * krs + kp);
            afk[g][kk] = s2b(o);
        }
    }

    // ---- fused gate+h GEMMs; epilogue = add v, sigmoid, multiply ----
    const short* wgo = wbf + 4 * WSZ;
    const short* wlo = wbf + 5 * WSZ;
    const float* vgo = vtab + 4 * 128;
    const float* vlo = vtab + 5 * 128;
    #pragma unroll
    for (int nt = 0; nt < 8; ++nt) {
        bf16x8 bg_[4], bh_[4];
        #pragma unroll
        for (int kk = 0; kk < 4; ++kk) {
            bg_[kk] = *(const bf16x8*)(wgo + (nt * 4 + kk) * 512 + fl);
            bh_[kk] = *(const bf16x8*)(wlo + (nt * 4 + kk) * 512 + fl);
        }
        f32x4 ag0 = {0.f,0.f,0.f,0.f}, ag1 = {0.f,0.f,0.f,0.f};
        f32x4 ah0 = {0.f,0.f,0.f,0.f}, ah1 = {0.f,0.f,0.f,0.f};
        #pragma unroll
        for (int kk = 0; kk < 4; ++kk) {
            ag0 = __builtin_amdgcn_mfma_f32_16x16x32_bf16(afx[0][kk], bg_[kk], ag0, 0, 0, 0);
            ag1 = __builtin_amdgcn_mfma_f32_16x16x32_bf16(afx[1][kk], bg_[kk], ag1, 0, 0, 0);
            ah0 = __builtin_amdgcn_mfma_f32_16x16x32_bf16(afk[0][kk], bh_[kk], ah0, 0, 0, 0);
            ah1 = __builtin_amdgcn_mfma_f32_16x16x32_bf16(afk[1][kk], bh_[kk], ah1, 0, 0, 0);
        }
        const int   col = nt * 16 + lr;
        const float vg  = vgo[col];
        const float vl  = vlo[col];
        #pragma unroll
        for (int r = 0; r < 4; ++r) {
            const size_t rowa = (size_t)batch * NN + row0 + lk * 4 + r;
            out[rowa * DD + col]        = sigf(ag0[r] + vg) * (ah0[r] + vl);
            out[(rowa + 16) * DD + col] = sigf(ag1[r] + vg) * (ah1[r] + vl);
        }
    }
}

extern "C" void kernel_launch(void* const* d_in, const int* in_sizes, int n_in,
                              void* d_out, int out_size, void* d_ws, size_t ws_size,
                              hipStream_t stream)
{
    const float* x    = (const float*)d_in[0];
    const float* lnw  = (const float*)d_in[1];
    const float* lnb  = (const float*)d_in[2];
    const float* Wla  = (const float*)d_in[3];
    const float* bla  = (const float*)d_in[4];
    const float* Wga  = (const float*)d_in[5];
    const float* bga  = (const float*)d_in[6];
    const float* Wlb  = (const float*)d_in[7];
    const float* blb  = (const float*)d_in[8];
    const float* Wgb  = (const float*)d_in[9];
    const float* bgb  = (const float*)d_in[10];
    const float* lnow = (const float*)d_in[11];
    const float* lnob = (const float*)d_in[12];
    const float* Wgo  = (const float*)d_in[13];
    const float* bgo  = (const float*)d_in[14];
    const float* Wlo  = (const float*)d_in[15];
    const float* blo  = (const float*)d_in[16];

    float* cbuf = (float*)d_ws;                                      // 4 MB
    short* wbf  = (short*)((char*)d_ws + (size_t)BB * NA * CC * 4);  // 6*32KB
    float* vtab = (float*)((char*)wbf + 6 * WSZ * sizeof(short));    // 6*512B
    float* out  = (float*)d_out;

    hipLaunchKernelGGL(kern_wcvt, dim3(67), dim3(256), 0, stream,
                       Wla, Wga, Wlb, Wgb, Wgo, Wlo,
                       lnw, lnb, lnow, lnob,
                       bla, bga, blb, bgb, bgo, blo, wbf, vtab);
    hipLaunchKernelGGL(kern_ab, dim3(BB * 512), dim3(64), 0, stream,
                       x, wbf, vtab, cbuf);
    hipLaunchKernelGGL(kern_out, dim3(BB * 2048), dim3(64), 0, stream,
                       x, wbf, vtab, cbuf, out);
}